// Round 6
// baseline (339.330 us; speedup 1.0000x reference)
//
#include <hip/hip_runtime.h>
#include <stdint.h>

typedef unsigned short u16;
typedef __attribute__((ext_vector_type(8))) short short8;
typedef __attribute__((ext_vector_type(4))) short short4v;
typedef __attribute__((ext_vector_type(4))) float floatx4;
typedef __attribute__((ext_vector_type(4))) int intx4;

#define B_ 2
#define N_ 2048
#define E_ 1024
#define H_ 16
#define HD_ 64
#define M_TOT (B_ * N_)   // 4096

__device__ __forceinline__ float bf2f(u16 h) {
    union { unsigned u; float f; } c; c.u = ((unsigned)h) << 16; return c.f;
}
__device__ __forceinline__ u16 f2bf(float f) {
    union { float f; unsigned u; } c; c.f = f;
    unsigned r = c.u + 0x7FFFu + ((c.u >> 16) & 1u);
    return (u16)(r >> 16);
}
__device__ __forceinline__ float silu_f(float x) { return x / (1.f + __expf(-x)); }

template <typename T> __device__ __forceinline__ void store_out(T* p, float v);
template <> __device__ __forceinline__ void store_out<u16>(u16* p, float v)    { *p = f2bf(v); }
template <> __device__ __forceinline__ void store_out<float>(float* p, float v) { *p = v; }

// Direct global->LDS 16B async copy. LDS dest = wave-uniform base + lane*16.
__device__ __forceinline__ void gll16(const void* g, void* l) {
    __builtin_amdgcn_global_load_lds(
        (const __attribute__((address_space(1))) void*)g,
        (__attribute__((address_space(3))) void*)l,
        16, 0, 0);
}

// relu(+pack) four fp32 -> 4 bf16 (round-half-up), order preserved.
__device__ __forceinline__ short4v relu_pack(floatx4 s) {
    union { float f; unsigned u; } c0, c1, c2, c3;
    c0.f = fmaxf(s[0], 0.f); c1.f = fmaxf(s[1], 0.f);
    c2.f = fmaxf(s[2], 0.f); c3.f = fmaxf(s[3], 0.f);
    unsigned lo = __builtin_amdgcn_perm(c1.u + 0x8000u, c0.u + 0x8000u, 0x07060302);
    unsigned hi = __builtin_amdgcn_perm(c3.u + 0x8000u, c2.u + 0x8000u, 0x07060302);
    union { unsigned v[2]; short4v s4; } r; r.v[0] = lo; r.v[1] = hi;
    return r.s4;
}

// ---------------------------------------------------------------------------
// fp32 -> bf16 for x (z=0, 2048 blocks) and 5 weights (z=1..5, 512 blocks).
// ---------------------------------------------------------------------------
__launch_bounds__(256, 4)
__global__ void cvt6(const float* __restrict__ s0, const float* __restrict__ s1,
                     const float* __restrict__ s2, const float* __restrict__ s3,
                     const float* __restrict__ s4, const float* __restrict__ s5,
                     u16* __restrict__ d0, u16* __restrict__ d1,
                     u16* __restrict__ d2, u16* __restrict__ d3,
                     u16* __restrict__ d4, u16* __restrict__ d5)
{
    const int z = blockIdx.z;
    if (z > 0 && blockIdx.x >= E_ * E_ / 2048) return;
    const float* src = (z == 0) ? s0 : (z == 1) ? s1 : (z == 2) ? s2
                     : (z == 3) ? s3 : (z == 4) ? s4 : s5;
    u16* dst         = (z == 0) ? d0 : (z == 1) ? d1 : (z == 2) ? d2
                     : (z == 3) ? d3 : (z == 4) ? d4 : d5;
    const int i = (blockIdx.x * 256 + threadIdx.x) * 8;
    floatx4 a = *(const floatx4*)(src + i);
    floatx4 b = *(const floatx4*)(src + i + 4);
    union { u16 h[8]; intx4 v; } o;
    o.h[0] = f2bf(a[0]); o.h[1] = f2bf(a[1]); o.h[2] = f2bf(a[2]); o.h[3] = f2bf(a[3]);
    o.h[4] = f2bf(b[0]); o.h[5] = f2bf(b[1]); o.h[6] = f2bf(b[2]); o.h[7] = f2bf(b[3]);
    *(intx4*)(dst + i) = o.v;
}

// ---------------------------------------------------------------------------
// gemm8p2: 256x256 8-phase rebuild, A/B HALF: handles z in {q,k} only.
// Grid (4,16,2)=128 blocks (1/CU on half the chip), 512 thr = 8 waves
// (2M x 4N), BK=64, 128 KiB LDS (2 K-tile dbuf; per buf: 2 M-halves x
// 2 k-planes of [128][32] u16, st_16x32-equiv XOR swizzle on 32-elem rows).
// Per tile 4 phases (1 barrier each), 16 MFMA/phase (quadrant x K=64):
//   P1: rd af[0-3]+bfr[0-1] | stage (t+1).A.h1 -> obuf | MFMA(0,0)
//   P2: rd af[4-7]          | stage (t+1).B.h0 -> obuf | MFMA(4,0)
//   P3: rd bfr[2-3]         | stage (t+1).B.h1 -> obuf | MFMA(4,2)
//   P4: (no reads)          | stage (t+2).A.h0 -> buf  | MFMA(0,2) | vmcnt(2)
// Write-safety: obuf never read during tile t; buf.A reads complete by
// P2-end barrier (af consumed via auto-lgkmcnt before P2 MFMA), so P4's
// A.h0 write to buf is ordered-after by the P3-end barrier. vmcnt(2) at the
// boundary forces all of tile t+1 landed, leaves (t+2).A.h0 in flight.
// This fixes R1's port: staggered P4->P3 staging window (2-5 phase slack)
// instead of everything-due-at-P1 with ~1 phase slack.
// ---------------------------------------------------------------------------
#define NT8 (E_ / 64)    // 16 K-tiles

__launch_bounds__(512, 2)
__global__ void gemm8p2(const u16* __restrict__ A,
                        const u16* __restrict__ W0, const u16* __restrict__ W1,
                        const float* __restrict__ bi0, const float* __restrict__ bi1,
                        u16* __restrict__ O0, u16* __restrict__ O1,
                        int scalemask)
{
    __shared__ u16 lds[65536];   // A: [0,32768) = 2buf x {h*8192 + p*4096}; B at +32768

    const int z = blockIdx.z;
    const u16* Wp   = z ? W1 : W0;
    const float* Bi = z ? bi1 : bi0;
    u16* Out        = z ? O1 : O0;
    const float osc = ((scalemask >> z) & 1) ? 0.125f : 1.0f;

    const int tid = threadIdx.x;
    const int wid = tid >> 6, lane = tid & 63, quad = lane >> 4, l16 = lane & 15;
    const int wm = wid >> 2, wn = wid & 3;     // 2 M-waves x 4 N-waves
    const int m0 = blockIdx.y * 256;
    const int n0 = blockIdx.x * 256;

    // read-side swizzled bases (u16 elems): plane [128][32], col ^= ((row>>3)&1)*16
    const int swz = ((l16 >> 3) & 1) * 16;
    const int raA = wm * 8192 + l16 * 32 + ((quad * 8) ^ swz);
    const int raB = (wn >> 1) * 8192 + ((wn & 1) * 64 + l16) * 32 + ((quad * 8) ^ swz);

    // staging: thread tid covers plane row tid>>2, linear cols (tid&3)*8;
    // inverse-swizzled global col so linear LDS write == swizzled layout.
    const int srow_s = tid >> 2;
    const int sce = ((tid & 3) * 8) ^ (((tid >> 5) & 1) * 16);
    const u16* As = A  + (size_t)(m0 + srow_s) * E_ + sce;
    const u16* Bs = Wp + (size_t)(n0 + srow_s) * E_ + sce;

#define ST_A8(t, h, bufx) if ((t) < NT8) {                                                      \
        gll16(As + (size_t)(h)*128*E_ + (t)*64,      &lds[(bufx)*16384 + (h)*8192 + wid*512]);  \
        gll16(As + (size_t)(h)*128*E_ + (t)*64 + 32, &lds[(bufx)*16384 + (h)*8192 + 4096 + wid*512]); }
#define ST_B8(t, h, bufx) if ((t) < NT8) {                                                      \
        gll16(Bs + (size_t)(h)*128*E_ + (t)*64,      &lds[32768 + (bufx)*16384 + (h)*8192 + wid*512]);  \
        gll16(Bs + (size_t)(h)*128*E_ + (t)*64 + 32, &lds[32768 + (bufx)*16384 + (h)*8192 + 4096 + wid*512]); }

    floatx4 acc[8][4];
    const floatx4 fz = {0.f, 0.f, 0.f, 0.f};
#pragma unroll
    for (int mi = 0; mi < 8; mi++)
#pragma unroll
        for (int bn = 0; bn < 4; bn++) acc[mi][bn] = fz;

    short8 af[8][2], bfr[2][2];

#define RD_A8(mlo, bufx)                                                               \
    _Pragma("unroll")                                                                  \
    for (int mi = 0; mi < 4; mi++) {                                                   \
        af[(mlo)+mi][0] = *(const short8*)&lds[(bufx)*16384 + raA + ((mlo)+mi)*512];   \
        af[(mlo)+mi][1] = *(const short8*)&lds[(bufx)*16384 + raA + 4096 + ((mlo)+mi)*512]; }
#define RD_B8(blo, bufx)                                                               \
    _Pragma("unroll")                                                                  \
    for (int bn = 0; bn < 2; bn++) {                                                   \
        bfr[bn][0] = *(const short8*)&lds[32768 + (bufx)*16384 + raB + ((blo)+bn)*512];   \
        bfr[bn][1] = *(const short8*)&lds[32768 + (bufx)*16384 + raB + 4096 + ((blo)+bn)*512]; }
#define MF8(mlo, blo)                                                                  \
    _Pragma("unroll")                                                                  \
    for (int mi = 0; mi < 4; mi++)                                                     \
        _Pragma("unroll")                                                              \
        for (int bn = 0; bn < 2; bn++) {                                               \
            acc[(mlo)+mi][(blo)+bn] = __builtin_amdgcn_mfma_f32_16x16x32_bf16(         \
                af[(mlo)+mi][0], bfr[bn][0], acc[(mlo)+mi][(blo)+bn], 0, 0, 0);        \
            acc[(mlo)+mi][(blo)+bn] = __builtin_amdgcn_mfma_f32_16x16x32_bf16(         \
                af[(mlo)+mi][1], bfr[bn][1], acc[(mlo)+mi][(blo)+bn], 0, 0, 0); }

    // prologue: tile 0 (all 8 planes) + tile 1 A.h0; vmcnt(2) -> t0 landed.
    ST_A8(0, 0, 0); ST_A8(0, 1, 0); ST_B8(0, 0, 0); ST_B8(0, 1, 0);
    ST_A8(1, 0, 1);
    asm volatile("s_waitcnt vmcnt(2)" ::: "memory");
    __builtin_amdgcn_s_barrier();

    for (int t = 0; t < NT8; t++) {
        const int buf = t & 1, ob = buf ^ 1;
        // P1
        RD_A8(0, buf); RD_B8(0, buf);
        ST_A8(t + 1, 1, ob);
        __builtin_amdgcn_s_setprio(1); MF8(0, 0); __builtin_amdgcn_s_setprio(0);
        __builtin_amdgcn_s_barrier();
        // P2
        RD_A8(4, buf);
        ST_B8(t + 1, 0, ob);
        __builtin_amdgcn_s_setprio(1); MF8(4, 0); __builtin_amdgcn_s_setprio(0);
        __builtin_amdgcn_s_barrier();
        // P3
        RD_B8(2, buf);
        ST_B8(t + 1, 1, ob);
        __builtin_amdgcn_s_setprio(1); MF8(4, 2); __builtin_amdgcn_s_setprio(0);
        __builtin_amdgcn_s_barrier();
        // P4 (no LDS reads; af[0-3]/bfr[2-3] still live)
        ST_A8(t + 2, 0, buf);
        __builtin_amdgcn_s_setprio(1); MF8(0, 2); __builtin_amdgcn_s_setprio(0);
        if (t + 2 < NT8) {
            asm volatile("s_waitcnt vmcnt(2)" ::: "memory");
        } else {
            asm volatile("s_waitcnt vmcnt(0)" ::: "memory");
        }
        __builtin_amdgcn_s_barrier();
    }
#undef ST_A8
#undef ST_B8
#undef RD_A8
#undef RD_B8
#undef MF8

    float bias_v[4];
#pragma unroll
    for (int bn = 0; bn < 4; bn++) bias_v[bn] = Bi[n0 + wn * 64 + bn * 16 + l16];

#pragma unroll
    for (int mi = 0; mi < 8; mi++) {
        const int row = m0 + wm * 128 + mi * 16 + quad * 4;
#pragma unroll
        for (int bn = 0; bn < 4; bn++) {
            const int col = n0 + wn * 64 + bn * 16 + l16;
#pragma unroll
            for (int r = 0; r < 4; r++) {
                float v = (acc[mi][bn][r] + bias_v[bn]) * osc;
                Out[(size_t)(row + r) * E_ + col] = f2bf(v);
            }
        }
    }
}

// ---------------------------------------------------------------------------
// GEMM (m97 structure, BK=32, NO swizzle -- R5 measured swizzle +4us on this
// latency-bound L3-fit kernel, m160's lesson). A/B HALF: z in {v,u} (silu).
// ---------------------------------------------------------------------------
template <typename OutT>
__launch_bounds__(256, 2)
__global__ void gemm4(const u16* __restrict__ A,
                      const u16* __restrict__ W0, const u16* __restrict__ W1,
                      const u16* __restrict__ W2, const u16* __restrict__ W3,
                      const float* __restrict__ bi0, const float* __restrict__ bi1,
                      const float* __restrict__ bi2, const float* __restrict__ bi3,
                      OutT* __restrict__ O0, OutT* __restrict__ O1,
                      OutT* __restrict__ O2, OutT* __restrict__ O3,
                      int actmask, int scalemask, int K)
{
    __shared__ u16 a_lds[128 * 32];   // 8 KB, unpadded (gll16 lane order)
    __shared__ u16 b_lds[128 * 32];

    const int z = blockIdx.z;
    const u16* W    = (z == 0) ? W0 : (z == 1) ? W1 : (z == 2) ? W2 : W3;
    const float* Bi = (z == 0) ? bi0 : (z == 1) ? bi1 : (z == 2) ? bi2 : bi3;
    OutT* Out       = (z == 0) ? O0 : (z == 1) ? O1 : (z == 2) ? O2 : O3;
    const bool act = (actmask >> z) & 1;
    const float osc = ((scalemask >> z) & 1) ? 0.125f : 1.0f;

    const int t    = threadIdx.x;
    const int wave = t >> 6, lane = t & 63, quad = lane >> 4, l16 = lane & 15;
    const int wm = wave >> 1, wn = wave & 1;
    const int m0 = blockIdx.y * 128;
    const int n0 = blockIdx.x * 128;

    floatx4 acc[4][4];
    const floatx4 fz = {0.f, 0.f, 0.f, 0.f};
    for (int i = 0; i < 4; i++)
        for (int j = 0; j < 4; j++) acc[i][j] = fz;

    const int ar = t >> 2;
    const int ac = (t & 3) * 8;
    const u16* Ag0 = A + (size_t)(m0 + ar) * K + ac;
    const u16* Ag1 = A + (size_t)(m0 + 64 + ar) * K + ac;
    const u16* Bg0 = W + (size_t)(n0 + ar) * K + ac;
    const u16* Bg1 = W + (size_t)(n0 + 64 + ar) * K + ac;
    u16* al0 = a_lds + wave * 512;
    u16* al1 = a_lds + 2048 + wave * 512;
    u16* bl0 = b_lds + wave * 512;
    u16* bl1 = b_lds + 2048 + wave * 512;

    for (int k0 = 0; k0 < K; k0 += 32) {
        __syncthreads();
        gll16(Ag0 + k0, al0);
        gll16(Ag1 + k0, al1);
        gll16(Bg0 + k0, bl0);
        gll16(Bg1 + k0, bl1);
        __syncthreads();

        short8 af[4], bfr[4];
        for (int i = 0; i < 4; i++)
            af[i]  = *(const short8*)&a_lds[(wm * 64 + i * 16 + l16) * 32 + quad * 8];
        for (int j = 0; j < 4; j++)
            bfr[j] = *(const short8*)&b_lds[(wn * 64 + j * 16 + l16) * 32 + quad * 8];
        for (int i = 0; i < 4; i++)
            for (int j = 0; j < 4; j++)
                acc[i][j] = __builtin_amdgcn_mfma_f32_16x16x32_bf16(af[i], bfr[j], acc[i][j], 0, 0, 0);
    }

    float bias_v[4];
    for (int j = 0; j < 4; j++) bias_v[j] = Bi[n0 + wn * 64 + j * 16 + l16];

    for (int i = 0; i < 4; i++) {
        const int row = m0 + wm * 64 + i * 16 + quad * 4;
        for (int j = 0; j < 4; j++) {
            const int col = n0 + wn * 64 + j * 16 + l16;
            for (int r = 0; r < 4; r++) {
                float v = acc[i][j][r] + bias_v[j];
                if (act) v = silu_f(v);
                v *= osc;
                store_out<OutT>(&Out[(size_t)(row + r) * E_ + col], v);
            }
        }
    }
}

// ---------------------------------------------------------------------------
// Output projection GEMM v2: 64x128 tile, 512 blocks (2/CU), 3-buffer 2-deep
// pipeline. A = gw is L3-hot scratch, so the L2-thrash failure mode of the
// projection pipeline doesn't apply. fp32 out + bias, no act.
// ---------------------------------------------------------------------------
__launch_bounds__(256, 2)
__global__ void gemm_out(const u16* __restrict__ A, const u16* __restrict__ W,
                         const float* __restrict__ Bi, float* __restrict__ Out,
                         int K)
{
    __shared__ u16 a_lds[3][64 * 32];    // 3 x 4 KB
    __shared__ u16 b_lds[3][128 * 32];   // 3 x 8 KB  -> 36 KB total

    const int t    = threadIdx.x;
    const int wave = t >> 6, lane = t & 63, quad = lane >> 4, l16 = lane & 15;
    const int m0 = blockIdx.y * 64;
    const int n0 = blockIdx.x * 128;

    floatx4 acc[4][2];
    const floatx4 fz = {0.f, 0.f, 0.f, 0.f};
    for (int i = 0; i < 4; i++)
        for (int j = 0; j < 2; j++) acc[i][j] = fz;

    const int ar = t >> 2;
    const int ac = (t & 3) * 8;
    const u16* Ag0 = A + (size_t)(m0 + ar) * K + ac;
    const u16* Bg0 = W + (size_t)(n0 + ar) * K + ac;
    const u16* Bg1 = W + (size_t)(n0 + 64 + ar) * K + ac;

    const int nt = K / 32;

#define GO_STAGE(tt, bi) {                                      \
        gll16(Ag0 + (tt) * 32, &a_lds[bi][wave * 512]);         \
        gll16(Bg0 + (tt) * 32, &b_lds[bi][wave * 512]);         \
        gll16(Bg1 + (tt) * 32, &b_lds[bi][2048 + wave * 512]); }

    GO_STAGE(0, 0);
    GO_STAGE(1, 1);
    asm volatile("s_waitcnt vmcnt(3)" ::: "memory");   // tile 0 landed
    __builtin_amdgcn_s_barrier();

    for (int tt = 0; tt < nt; tt++) {
        const int bi = tt % 3;
        if (tt + 2 < nt) {
            GO_STAGE(tt + 2, (tt + 2) % 3);
        }
        short8 af[4], bfr[2];
#pragma unroll
        for (int i = 0; i < 4; i++)
            af[i]  = *(const short8*)&a_lds[bi][(i * 16 + l16) * 32 + quad * 8];
#pragma unroll
        for (int j = 0; j < 2; j++)
            bfr[j] = *(const short8*)&b_lds[bi][(wave * 32 + j * 16 + l16) * 32 + quad * 8];
#pragma unroll
        for (int i = 0; i < 4; i++)
#pragma unroll
            for (int j = 0; j < 2; j++)
                acc[i][j] = __builtin_amdgcn_mfma_f32_16x16x32_bf16(af[i], bfr[j], acc[i][j], 0, 0, 0);
        if (tt + 2 < nt) {
            asm volatile("s_waitcnt vmcnt(3)" ::: "memory");   // t+1 landed
        } else {
            asm volatile("s_waitcnt vmcnt(0)" ::: "memory");   // tail drain
        }
        __builtin_amdgcn_s_barrier();
    }
#undef GO_STAGE

    float bias_v[2];
    for (int j = 0; j < 2; j++) bias_v[j] = Bi[n0 + wave * 32 + j * 16 + l16];

    for (int i = 0; i < 4; i++) {
        const int row = m0 + i * 16 + quad * 4;
        for (int j = 0; j < 2; j++) {
            const int col = n0 + wave * 32 + j * 16 + l16;
            for (int r = 0; r < 4; r++)
                Out[(size_t)(row + r) * E_ + col] = acc[i][j][r] + bias_v[j];
        }
    }
}

// ---------------------------------------------------------------------------
// Attention v8: v7 structure (async-STAGE dbuf) + XCD swizzle, now KSPLIT=4
// with __launch_bounds__(256,4): occupancy was GRID-limited (512 blocks =
// 2/CU regardless of resources; KSPLIT 2 vs 4 at 2/CU measured identical).
// Grid 1024 + 4 blocks/CU (LDS 4 x 36.9 = 147 KB < 160, VGPR 76 < 128)
// -> 16 waves/CU to hide the serial QK->relu->PV chain (MfmaUtil 26% +
// VALUBusy 31% = 43% idle).
// ---------------------------------------------------------------------------
#define LK 72
#define LV 72
#define KSPLIT 4
#define KCHUNK (N_ / KSPLIT)    // 512 keys per z
#define NKT (KCHUNK / 64)       // 8 tiles

__launch_bounds__(256, 4)
__global__ void attn(const u16* __restrict__ Q, const u16* __restrict__ Kk,
                     const u16* __restrict__ V,
                     u16* __restrict__ P0, u16* __restrict__ P1,
                     u16* __restrict__ P2, u16* __restrict__ P3)
{
    __shared__ u16 k_lds[2][64 * LK];    // row-permuted [keyslot][d], dbuf
    __shared__ u16 v_lds[2][64 * LV];    // [d][key], padded stride, dbuf

    // XCD-chunked swizzle over (8,32,4), nwg=1024, q=128.
    const int lin = blockIdx.x + blockIdx.y * 8 + blockIdx.z * 256;
    const int swz = (lin & 7) * 128 + (lin >> 3);
    const int z   = swz >> 8;          // 0..3
    const int bh  = (swz >> 3) & 31;   // 0..31
    const int qb  = swz & 7;           // 0..7

    const int b = bh >> 4, h = bh & 15;
    u16* __restrict__ Oa = (z == 0) ? P0 : (z == 1) ? P1 : (z == 2) ? P2 : P3;
    const int key_base = z * KCHUNK;

    const int t = threadIdx.x;
    const int wave = t >> 6, lane = t & 63, quad = lane >> 4, l16 = lane & 15;
    const int q0 = qb * 256 + wave * 64;
    const size_t base = (size_t)b * N_ * E_ + h * HD_;

    short8 aq[4][2];
    for (int mi = 0; mi < 4; mi++)
        for (int ks = 0; ks < 2; ks++)
            aq[mi][ks] = *(const short8*)(Q + base + (size_t)(q0 + mi * 16 + l16) * E_ + ks * 32 + quad * 8);

    floatx4 o[4][4];
    const floatx4 fz = {0.f, 0.f, 0.f, 0.f};
    for (int mi = 0; mi < 4; mi++)
        for (int nd = 0; nd < 4; nd++) o[mi][nd] = fz;

    const int srow = t >> 2, sseg = (t & 3) * 16;
    const int prow = (srow & 32) + (((srow >> 2) & 1) << 4)
                   + (((srow >> 3) & 3) << 2) + (srow & 3);
    const u16* Ksrc = Kk + base + (size_t)(key_base + srow) * E_ + sseg;
    const u16* Vsrc = V + base + (size_t)(key_base + srow) * E_ + sseg;
    const int kofs = prow * LK + sseg;

    // prologue: tile 0 -> regs -> buf0
    intx4 kv0 = *(const intx4*)(Ksrc);
    intx4 kv1 = *(const intx4*)(Ksrc + 8);
    intx4 vv0 = *(const intx4*)(Vsrc);
    intx4 vv1 = *(const intx4*)(Vsrc + 8);
    {
        *(intx4*)(&k_lds[0][kofs])     = kv0;
        *(intx4*)(&k_lds[0][kofs + 8]) = kv1;
        const u16* v0p = (const u16*)&vv0;
        const u16* v1p = (const u16*)&vv1;
        for (int i = 0; i < 8; i++) {
            v_lds[0][(sseg + i) * LV + srow]     = v0p[i];
            v_lds[0][(sseg + 8 + i) * LV + srow] = v1p[i];
        }
    }

    for (int kt = 0; kt < NKT; kt++) {
        __syncthreads();    // buf[kt&1] writes visible; prev reads of buf^1 done
        const int cur = kt & 1;

        // issue next tile's global loads NOW (hide under compute)
        if (kt + 1 < NKT) {
            const u16* kg = Ksrc + (size_t)((kt + 1) * 64) * E_;
            const u16* vg = Vsrc + (size_t)((kt + 1) * 64) * E_;
            kv0 = *(const intx4*)(kg);
            kv1 = *(const intx4*)(kg + 8);
            vv0 = *(const intx4*)(vg);
            vv1 = *(const intx4*)(vg + 8);
        }

        for (int g = 0; g < 2; g++) {   // 32-key group
            short8 ka[2][2];
            for (int tp = 0; tp < 2; tp++)
                for (int ks = 0; ks < 2; ks++)
                    ka[tp][ks] = *(const short8*)&k_lds[cur][(g * 32 + tp * 16 + l16) * LK + ks * 32 + quad * 8];
            short8 bv[4];
            for (int nd = 0; nd < 4; nd++)
                bv[nd] = *(const short8*)&v_lds[cur][(nd * 16 + l16) * LV + g * 32 + quad * 8];

            for (int mi = 0; mi < 4; mi++) {
                floatx4 c0 = __builtin_amdgcn_mfma_f32_16x16x32_bf16(ka[0][0], aq[mi][0], fz, 0, 0, 0);
                c0 = __builtin_amdgcn_mfma_f32_16x16x32_bf16(ka[0][1], aq[mi][1], c0, 0, 0, 0);
                floatx4 c1 = __builtin_amdgcn_mfma_f32_16x16x32_bf16(ka[1][0], aq[mi][0], fz, 0, 0, 0);
                c1 = __builtin_amdgcn_mfma_f32_16x16x32_bf16(ka[1][1], aq[mi][1], c1, 0, 0, 0);
                union { short4v h[2]; short8 s8; } sf;
                sf.h[0] = relu_pack(c0);
                sf.h[1] = relu_pack(c1);
                for (int nd = 0; nd < 4; nd++)
                    o[mi][nd] = __builtin_amdgcn_mfma_f32_16x16x32_bf16(sf.s8, bv[nd], o[mi][nd], 0, 0, 0);
            }
        }

        // write next tile into buf^1
        if (kt + 1 < NKT) {
            const int nxt = cur ^ 1;
            *(intx4*)(&k_lds[nxt][kofs])     = kv0;
            *(intx4*)(&k_lds[nxt][kofs + 8]) = kv1;
            const u16* v0p = (const u16*)&vv0;
            const u16* v1p = (const u16*)&vv1;
            for (int i = 0; i < 8; i++) {
                v_lds[nxt][(sseg + i) * LV + srow]     = v0p[i];
                v_lds[nxt][(sseg + 8 + i) * LV + srow] = v1p[i];
            }
        }
    }

    for (int mi = 0; mi < 4; mi++)
        for (int nd = 0; nd < 4; nd++)
            for (int r = 0; r < 4; r++)
                Oa[(size_t)(b * N_ + q0 + mi * 16 + quad * 4 + r) * E_ + h * HD_ + nd * 16 + l16] =
                    f2bf(o[mi][nd][r]);
}

// ---------------------------------------------------------------------------
// LayerNorm over E=1024 of (P0+P1+P2+P3) + gate by u, emit bf16. 1 block/row.
// ---------------------------------------------------------------------------
__launch_bounds__(256, 4)
__global__ void ln_gate(const u16* __restrict__ P0, const u16* __restrict__ P1,
                        const u16* __restrict__ P2, const u16* __restrict__ P3,
                        const u16* __restrict__ U,
                        const float* __restrict__ G, const float* __restrict__ Bb,
                        u16* __restrict__ Out)
{
    const int row = blockIdx.x;
    const int t = threadIdx.x;
    const size_t idx = (size_t)row * E_ + t * 4;
    const short4v a0 = *(const short4v*)(P0 + idx);
    const short4v a1 = *(const short4v*)(P1 + idx);
    const short4v a2 = *(const short4v*)(P2 + idx);
    const short4v a3 = *(const short4v*)(P3 + idx);
    floatx4 v;
    for (int i = 0; i < 4; i++)
        v[i] = bf2f((u16)a0[i]) + bf2f((u16)a1[i]) + bf2f((u16)a2[i]) + bf2f((u16)a3[i]);
    float s  = v[0] + v[1] + v[2] + v[3];
    float ss = v[0] * v[0] + v[1] * v[1] + v[2] * v[2] + v[3] * v[3];
    for (int off = 32; off; off >>= 1) {
        s  += __shfl_down(s, off, 64);
        ss += __shfl_down(ss, off, 64);
    }
    __shared__ float red[8];
    const int wave = t >> 6, lane = t & 63;
    if (lane == 0) { red[wave] = s; red[4 + wave] = ss; }
    __syncthreads();
    const float S  = red[0] + red[1] + red[2] + red[3];
    const float SS = red[4] + red[5] + red[6] + red[7];
    const float mu  = S * (1.f / E_);
    const float var = SS * (1.f / E_) - mu * mu;
    const float rstd = rsqrtf(var + 1e-5f);

    short4v outv;
    for (int i = 0; i < 4; i++) {
        const int e = t * 4 + i;
        float y = (v[i] - mu) * rstd * G[e] + Bb[e];
        y *= bf2f(U[idx + i]);
        outv[i] = (short)f2bf(y);
    }
    *(short4v*)(Out + idx) = outv;
}

// ---------------------------------------------------------------------------
extern "C" void kernel_launch(void* const* d_in, const int* in_sizes, int n_in,
                              void* d_out, int out_size, void* d_ws, size_t ws_size,
                              hipStream_t stream)
{
    const float* x   = (const float*)d_in[0];
    const float* Wq  = (const float*)d_in[1];
    const float* bq  = (const float*)d_in[2];
    const float* Wk  = (const float*)d_in[3];
    const float* bk  = (const float*)d_in[4];
    const float* Wv  = (const float*)d_in[5];
    const float* bv  = (const float*)d_in[6];
    const float* Wu  = (const float*)d_in[7];
    const float* bu  = (const float*)d_in[8];
    const float* Wo  = (const float*)d_in[9];
    const float* bo  = (const float*)d_in[10];
    const float* lng = (const float*)d_in[11];
    const float* lnb = (const float*)d_in[12];

    char* ws = (char*)d_ws;
    u16*  qw  = (u16*)(ws);                      // 8 MB (q row-major, pre-scaled 1/8)
    u16*  kw  = (u16*)(ws + 8388608);            // 8 MB (K row-major)
    u16*  vw  = (u16*)(ws + 16777216);           // 8 MB (V row-major)
    u16*  uw  = (u16*)(ws + 25165824);           // 8 MB (u row-major)
    u16*  p0  = (u16*)(ws + 33554432);           // 8 MB bf16 attn partial z=0
    u16*  p1  = (u16*)(ws + 41943040);           // 8 MB bf16 attn partial z=1
    u16*  xb  = (u16*)(ws + 50331648);           // 8 MB x->bf16
    u16*  wbq = (u16*)(ws + 58720256);           // 2 MB each, bf16 weights
    u16*  wbk = (u16*)(ws + 60817408);
    u16*  wbv = (u16*)(ws + 62914560);
    u16*  wbu = (u16*)(ws + 65011712);
    u16*  wbo = (u16*)(ws + 67108864);
    u16*  gw  = (u16*)(ws);                      // reuses q buffer after attn

    float* out = (float*)d_out;
    u16*  p2  = (u16*)d_out;                     // d_out as scratch: partials z=2,3
    u16*  p3  = (u16*)d_out + 4194304;

    // dtype prep (x + 5 weights, one launch)
    cvt6<<<dim3(M_TOT * E_ / 2048, 1, 6), dim3(256, 1, 1), 0, stream>>>(
        x, Wq, Wk, Wv, Wu, Wo, xb, wbq, wbk, wbv, wbu, wbo);
    // A/B within-run: q,k on the 8-phase rebuild (128 blocks, 1/CU half-chip)
    gemm8p2<<<dim3(E_ / 256, M_TOT / 256, 2), dim3(512, 1, 1), 0, stream>>>(
        xb, wbq, wbk, bq, bk, qw, kw, 0x1);
    // v,u on proven gemm4 (silu), no swizzle
    gemm4<u16><<<dim3(8, 32, 2), dim3(256, 1, 1), 0, stream>>>(
        xb, wbv, wbu, wbv, wbu, bv, bu, bv, bu, vw, uw, vw, uw, 0x3, 0x0, E_);
    // attention v8: KSPLIT=4 + 4 blocks/CU + XCD swizzle
    attn<<<dim3(N_ / 256, B_ * H_, KSPLIT), dim3(256, 1, 1), 0, stream>>>(
        qw, kw, vw, p0, p1, p2, p3);
    // layernorm(sum of 4 partials) + gate
    ln_gate<<<dim3(M_TOT, 1, 1), dim3(256, 1, 1), 0, stream>>>(
        p0, p1, p2, p3, uw, lng, lnb, gw);
    // output projection -> fp32 d_out: 64x128 tiles, 3-buf pipelined
    gemm_out<<<dim3(E_ / 128, M_TOT / 64, 1), dim3(256, 1, 1), 0, stream>>>(gw, wbo, bo, out, E_);
}

// Round 7
// 215.954 us; speedup vs baseline: 1.5713x; 1.5713x over previous
//
#include <hip/hip_runtime.h>
#include <stdint.h>

typedef unsigned short u16;
typedef __attribute__((ext_vector_type(8))) short short8;
typedef __attribute__((ext_vector_type(4))) short short4v;
typedef __attribute__((ext_vector_type(4))) float floatx4;
typedef __attribute__((ext_vector_type(4))) int intx4;

#define B_ 2
#define N_ 2048
#define E_ 1024
#define H_ 16
#define HD_ 64
#define M_TOT (B_ * N_)   // 4096

__device__ __forceinline__ float bf2f(u16 h) {
    union { unsigned u; float f; } c; c.u = ((unsigned)h) << 16; return c.f;
}
__device__ __forceinline__ u16 f2bf(float f) {
    union { float f; unsigned u; } c; c.f = f;
    unsigned r = c.u + 0x7FFFu + ((c.u >> 16) & 1u);
    return (u16)(r >> 16);
}
__device__ __forceinline__ float silu_f(float x) { return x / (1.f + __expf(-x)); }

template <typename T> __device__ __forceinline__ void store_out(T* p, float v);
template <> __device__ __forceinline__ void store_out<u16>(u16* p, float v)    { *p = f2bf(v); }
template <> __device__ __forceinline__ void store_out<float>(float* p, float v) { *p = v; }

// Direct global->LDS 16B async copy. LDS dest = wave-uniform base + lane*16.
__device__ __forceinline__ void gll16(const void* g, void* l) {
    __builtin_amdgcn_global_load_lds(
        (const __attribute__((address_space(1))) void*)g,
        (__attribute__((address_space(3))) void*)l,
        16, 0, 0);
}

// relu(+pack) four fp32 -> 4 bf16 (round-half-up), order preserved.
__device__ __forceinline__ short4v relu_pack(floatx4 s) {
    union { float f; unsigned u; } c0, c1, c2, c3;
    c0.f = fmaxf(s[0], 0.f); c1.f = fmaxf(s[1], 0.f);
    c2.f = fmaxf(s[2], 0.f); c3.f = fmaxf(s[3], 0.f);
    unsigned lo = __builtin_amdgcn_perm(c1.u + 0x8000u, c0.u + 0x8000u, 0x07060302);
    unsigned hi = __builtin_amdgcn_perm(c3.u + 0x8000u, c2.u + 0x8000u, 0x07060302);
    union { unsigned v[2]; short4v s4; } r; r.v[0] = lo; r.v[1] = hi;
    return r.s4;
}

// ---------------------------------------------------------------------------
// fp32 -> bf16 for x (z=0, 2048 blocks) and 5 weights (z=1..5, 512 blocks).
// ---------------------------------------------------------------------------
__launch_bounds__(256, 4)
__global__ void cvt6(const float* __restrict__ s0, const float* __restrict__ s1,
                     const float* __restrict__ s2, const float* __restrict__ s3,
                     const float* __restrict__ s4, const float* __restrict__ s5,
                     u16* __restrict__ d0, u16* __restrict__ d1,
                     u16* __restrict__ d2, u16* __restrict__ d3,
                     u16* __restrict__ d4, u16* __restrict__ d5)
{
    const int z = blockIdx.z;
    if (z > 0 && blockIdx.x >= E_ * E_ / 2048) return;
    const float* src = (z == 0) ? s0 : (z == 1) ? s1 : (z == 2) ? s2
                     : (z == 3) ? s3 : (z == 4) ? s4 : s5;
    u16* dst         = (z == 0) ? d0 : (z == 1) ? d1 : (z == 2) ? d2
                     : (z == 3) ? d3 : (z == 4) ? d4 : d5;
    const int i = (blockIdx.x * 256 + threadIdx.x) * 8;
    floatx4 a = *(const floatx4*)(src + i);
    floatx4 b = *(const floatx4*)(src + i + 4);
    union { u16 h[8]; intx4 v; } o;
    o.h[0] = f2bf(a[0]); o.h[1] = f2bf(a[1]); o.h[2] = f2bf(a[2]); o.h[3] = f2bf(a[3]);
    o.h[4] = f2bf(b[0]); o.h[5] = f2bf(b[1]); o.h[6] = f2bf(b[2]); o.h[7] = f2bf(b[3]);
    *(intx4*)(dst + i) = o.v;
}

// ---------------------------------------------------------------------------
// GEMM (m97 structure, BK=32): C[M,1024] = act( A @ W^T + bias ) [*osc]
// The PROVEN projection kernel: 52.5-53.1 us across R1/R2 replicas. NO
// blockIdx swizzle (measured +4 us on this L3-fit latency-bound kernel, R5).
// All structural escapes measured worse: 256^2 8-phase 77 us (R3, unstable
// codegen); 3-buf counted-vmcnt 66 us w/ FETCH 37->70 MB (R4); swizzle 57 us
// (R5). This IS the floor for this kernel at HIP source (m131-m141).
// ---------------------------------------------------------------------------
template <typename OutT>
__launch_bounds__(256, 2)
__global__ void gemm4(const u16* __restrict__ A,
                      const u16* __restrict__ W0, const u16* __restrict__ W1,
                      const u16* __restrict__ W2, const u16* __restrict__ W3,
                      const float* __restrict__ bi0, const float* __restrict__ bi1,
                      const float* __restrict__ bi2, const float* __restrict__ bi3,
                      OutT* __restrict__ O0, OutT* __restrict__ O1,
                      OutT* __restrict__ O2, OutT* __restrict__ O3,
                      int actmask, int scalemask, int K)
{
    __shared__ u16 a_lds[128 * 32];   // 8 KB, unpadded (gll16 lane order)
    __shared__ u16 b_lds[128 * 32];

    const int z = blockIdx.z;
    const u16* W    = (z == 0) ? W0 : (z == 1) ? W1 : (z == 2) ? W2 : W3;
    const float* Bi = (z == 0) ? bi0 : (z == 1) ? bi1 : (z == 2) ? bi2 : bi3;
    OutT* Out       = (z == 0) ? O0 : (z == 1) ? O1 : (z == 2) ? O2 : O3;
    const bool act = (actmask >> z) & 1;
    const float osc = ((scalemask >> z) & 1) ? 0.125f : 1.0f;

    const int t    = threadIdx.x;
    const int wave = t >> 6, lane = t & 63, quad = lane >> 4, l16 = lane & 15;
    const int wm = wave >> 1, wn = wave & 1;
    const int m0 = blockIdx.y * 128;
    const int n0 = blockIdx.x * 128;

    floatx4 acc[4][4];
    const floatx4 fz = {0.f, 0.f, 0.f, 0.f};
    for (int i = 0; i < 4; i++)
        for (int j = 0; j < 4; j++) acc[i][j] = fz;

    // staging map: thread t -> LDS bytes [t*16, t*16+16) -> row t/4, col (t%4)*8
    const int ar = t >> 2;
    const int ac = (t & 3) * 8;
    const u16* Ag0 = A + (size_t)(m0 + ar) * K + ac;
    const u16* Ag1 = A + (size_t)(m0 + 64 + ar) * K + ac;
    const u16* Bg0 = W + (size_t)(n0 + ar) * K + ac;
    const u16* Bg1 = W + (size_t)(n0 + 64 + ar) * K + ac;
    u16* al0 = a_lds + wave * 512;
    u16* al1 = a_lds + 2048 + wave * 512;
    u16* bl0 = b_lds + wave * 512;
    u16* bl1 = b_lds + 2048 + wave * 512;

    for (int k0 = 0; k0 < K; k0 += 32) {
        __syncthreads();
        gll16(Ag0 + k0, al0);
        gll16(Ag1 + k0, al1);
        gll16(Bg0 + k0, bl0);
        gll16(Bg1 + k0, bl1);
        __syncthreads();

        short8 af[4], bfr[4];
        for (int i = 0; i < 4; i++)
            af[i]  = *(const short8*)&a_lds[(wm * 64 + i * 16 + l16) * 32 + quad * 8];
        for (int j = 0; j < 4; j++)
            bfr[j] = *(const short8*)&b_lds[(wn * 64 + j * 16 + l16) * 32 + quad * 8];
        for (int i = 0; i < 4; i++)
            for (int j = 0; j < 4; j++)
                acc[i][j] = __builtin_amdgcn_mfma_f32_16x16x32_bf16(af[i], bfr[j], acc[i][j], 0, 0, 0);
    }

    float bias_v[4];
    for (int j = 0; j < 4; j++) bias_v[j] = Bi[n0 + wn * 64 + j * 16 + l16];

    for (int i = 0; i < 4; i++) {
        const int row = m0 + wm * 64 + i * 16 + quad * 4;
        for (int j = 0; j < 4; j++) {
            const int col = n0 + wn * 64 + j * 16 + l16;
            for (int r = 0; r < 4; r++) {
                float v = acc[i][j][r] + bias_v[j];
                if (act) v = silu_f(v);
                v *= osc;
                store_out<OutT>(&Out[(size_t)(row + r) * E_ + col], v);
            }
        }
    }
}

// ---------------------------------------------------------------------------
// Output projection GEMM v2: 64x128 tile, 512 blocks (2/CU), 3-buffer 2-deep
// pipeline (counted vmcnt, never 0 mid-loop). A = gw is L3-hot scratch and
// W = wbo is 2 MB, so the L2-thrash failure mode seen on the projection
// pipeline doesn't apply here. fp32 out + bias, no act.
// ---------------------------------------------------------------------------
__launch_bounds__(256, 2)
__global__ void gemm_out(const u16* __restrict__ A, const u16* __restrict__ W,
                         const float* __restrict__ Bi, float* __restrict__ Out,
                         int K)
{
    __shared__ u16 a_lds[3][64 * 32];    // 3 x 4 KB
    __shared__ u16 b_lds[3][128 * 32];   // 3 x 8 KB  -> 36 KB total

    const int t    = threadIdx.x;
    const int wave = t >> 6, lane = t & 63, quad = lane >> 4, l16 = lane & 15;
    const int m0 = blockIdx.y * 64;
    const int n0 = blockIdx.x * 128;

    floatx4 acc[4][2];
    const floatx4 fz = {0.f, 0.f, 0.f, 0.f};
    for (int i = 0; i < 4; i++)
        for (int j = 0; j < 2; j++) acc[i][j] = fz;

    const int ar = t >> 2;
    const int ac = (t & 3) * 8;
    const u16* Ag0 = A + (size_t)(m0 + ar) * K + ac;
    const u16* Bg0 = W + (size_t)(n0 + ar) * K + ac;
    const u16* Bg1 = W + (size_t)(n0 + 64 + ar) * K + ac;

    const int nt = K / 32;

#define GO_STAGE(tt, bi) {                                      \
        gll16(Ag0 + (tt) * 32, &a_lds[bi][wave * 512]);         \
        gll16(Bg0 + (tt) * 32, &b_lds[bi][wave * 512]);         \
        gll16(Bg1 + (tt) * 32, &b_lds[bi][2048 + wave * 512]); }

    GO_STAGE(0, 0);
    GO_STAGE(1, 1);
    asm volatile("s_waitcnt vmcnt(3)" ::: "memory");   // tile 0 landed
    __builtin_amdgcn_s_barrier();

    for (int tt = 0; tt < nt; tt++) {
        const int bi = tt % 3;
        if (tt + 2 < nt) {
            GO_STAGE(tt + 2, (tt + 2) % 3);
        }
        short8 af[4], bfr[2];
#pragma unroll
        for (int i = 0; i < 4; i++)
            af[i]  = *(const short8*)&a_lds[bi][(i * 16 + l16) * 32 + quad * 8];
#pragma unroll
        for (int j = 0; j < 2; j++)
            bfr[j] = *(const short8*)&b_lds[bi][(wave * 32 + j * 16 + l16) * 32 + quad * 8];
#pragma unroll
        for (int i = 0; i < 4; i++)
#pragma unroll
            for (int j = 0; j < 2; j++)
                acc[i][j] = __builtin_amdgcn_mfma_f32_16x16x32_bf16(af[i], bfr[j], acc[i][j], 0, 0, 0);
        if (tt + 2 < nt) {
            asm volatile("s_waitcnt vmcnt(3)" ::: "memory");   // t+1 landed
        } else {
            asm volatile("s_waitcnt vmcnt(0)" ::: "memory");   // tail drain
        }
        __builtin_amdgcn_s_barrier();
    }
#undef GO_STAGE

    float bias_v[2];
    for (int j = 0; j < 2; j++) bias_v[j] = Bi[n0 + wave * 32 + j * 16 + l16];

    for (int i = 0; i < 4; i++) {
        const int row = m0 + i * 16 + quad * 4;
        for (int j = 0; j < 2; j++) {
            const int col = n0 + wave * 32 + j * 16 + l16;
            for (int r = 0; r < 4; r++)
                Out[(size_t)(row + r) * E_ + col] = acc[i][j][r] + bias_v[j];
        }
    }
}

// ---------------------------------------------------------------------------
// Attention v6 (the PROVEN config: 50.3-50.6 us, 5 replicas in R2 bench):
// O = relu(Q K^T) @ V, Q pre-scaled 1/8. KSPLIT=2, single-buffered LDS,
// 2 barriers/tile, NO blockIdx swizzle (swizzle measured +30 us on attn,
// R3->R4 accounting; KSPLIT4+4/CU+swizzle exploded to 147 us in R6 via L2
// thrash: FETCH 73->274 MB). vtrans fused into staging: V read row-major
// coalesced, transposed into padded [64][72] LDS.
// QK: S^T = K Q^T (x32), K rows ROW-PERMUTED (LK=72) so two 16-key C-tiles
// relu_pack in-register into the exact x32 PV A-frag (full-rate x32 PV).
// Block: 256 q (4 waves x 64 q) x (b,h) x key-chunk z, 64-key tiles.
// ---------------------------------------------------------------------------
#define LK 72
#define LV 72
#define KSPLIT 2
#define KCHUNK (N_ / KSPLIT)    // 1024 keys per z

__launch_bounds__(256, 2)
__global__ void attn(const u16* __restrict__ Q, const u16* __restrict__ Kk,
                     const u16* __restrict__ V,
                     u16* __restrict__ P0, u16* __restrict__ P1)
{
    __shared__ u16 k_lds[64 * LK];    // row-permuted [keyslot][d]
    __shared__ u16 v_lds[64 * LV];    // [d][key], padded stride

    const int bh = blockIdx.y;
    const int b = bh >> 4, h = bh & 15;
    const int z = blockIdx.z;
    u16* __restrict__ Oa = (z == 0) ? P0 : P1;
    const int key_base = z * KCHUNK;

    const int t = threadIdx.x;
    const int wave = t >> 6, lane = t & 63, quad = lane >> 4, l16 = lane & 15;
    const int q0 = blockIdx.x * 256 + wave * 64;
    const size_t base = (size_t)b * N_ * E_ + h * HD_;

    short8 aq[4][2];
    for (int mi = 0; mi < 4; mi++)
        for (int ks = 0; ks < 2; ks++)
            aq[mi][ks] = *(const short8*)(Q + base + (size_t)(q0 + mi * 16 + l16) * E_ + ks * 32 + quad * 8);

    floatx4 o[4][4];
    const floatx4 fz = {0.f, 0.f, 0.f, 0.f};
    for (int mi = 0; mi < 4; mi++)
        for (int nd = 0; nd < 4; nd++) o[mi][nd] = fz;

    const int srow = t >> 2, sseg = (t & 3) * 16;
    const int prow = (srow & 32) + (((srow >> 2) & 1) << 4)
                   + (((srow >> 3) & 3) << 2) + (srow & 3);
    const u16* Ksrc = Kk + base + (size_t)(key_base + srow) * E_ + sseg;
    u16* kdst = &k_lds[prow * LK + sseg];
    const u16* Vsrc = V + base + (size_t)(key_base + srow) * E_ + sseg;

    for (int kt = 0; kt < KCHUNK / 64; kt++) {
        __syncthreads();
        const u16* kg = Ksrc + (size_t)(kt * 64) * E_;
        const u16* vg = Vsrc + (size_t)(kt * 64) * E_;
        intx4 kv0 = *(const intx4*)(kg);
        intx4 kv1 = *(const intx4*)(kg + 8);
        intx4 vv0 = *(const intx4*)(vg);
        intx4 vv1 = *(const intx4*)(vg + 8);
        *(intx4*)(kdst)     = kv0;
        *(intx4*)(kdst + 8) = kv1;
        const u16* v0p = (const u16*)&vv0;
        const u16* v1p = (const u16*)&vv1;
        for (int i = 0; i < 8; i++) {
            v_lds[(sseg + i) * LV + srow]     = v0p[i];
            v_lds[(sseg + 8 + i) * LV + srow] = v1p[i];
        }
        __syncthreads();

        for (int g = 0; g < 2; g++) {   // 32-key group
            short8 ka[2][2];
            for (int tp = 0; tp < 2; tp++)
                for (int ks = 0; ks < 2; ks++)
                    ka[tp][ks] = *(const short8*)&k_lds[(g * 32 + tp * 16 + l16) * LK + ks * 32 + quad * 8];
            short8 bv[4];
            for (int nd = 0; nd < 4; nd++)
                bv[nd] = *(const short8*)&v_lds[(nd * 16 + l16) * LV + g * 32 + quad * 8];

            for (int mi = 0; mi < 4; mi++) {
                floatx4 c0 = __builtin_amdgcn_mfma_f32_16x16x32_bf16(ka[0][0], aq[mi][0], fz, 0, 0, 0);
                c0 = __builtin_amdgcn_mfma_f32_16x16x32_bf16(ka[0][1], aq[mi][1], c0, 0, 0, 0);
                floatx4 c1 = __builtin_amdgcn_mfma_f32_16x16x32_bf16(ka[1][0], aq[mi][0], fz, 0, 0, 0);
                c1 = __builtin_amdgcn_mfma_f32_16x16x32_bf16(ka[1][1], aq[mi][1], c1, 0, 0, 0);
                union { short4v h[2]; short8 s8; } sf;
                sf.h[0] = relu_pack(c0);
                sf.h[1] = relu_pack(c1);
                for (int nd = 0; nd < 4; nd++)
                    o[mi][nd] = __builtin_amdgcn_mfma_f32_16x16x32_bf16(sf.s8, bv[nd], o[mi][nd], 0, 0, 0);
            }
        }
    }

    for (int mi = 0; mi < 4; mi++)
        for (int nd = 0; nd < 4; nd++)
            for (int r = 0; r < 4; r++)
                Oa[(size_t)(b * N_ + q0 + mi * 16 + quad * 4 + r) * E_ + h * HD_ + nd * 16 + l16] =
                    f2bf(o[mi][nd][r]);
}

// ---------------------------------------------------------------------------
// LayerNorm over E=1024 of (P0+P1) + gate by u, emit bf16. 1 block/row.
// ---------------------------------------------------------------------------
__launch_bounds__(256, 4)
__global__ void ln_gate(const u16* __restrict__ P0, const u16* __restrict__ P1,
                        const u16* __restrict__ U,
                        const float* __restrict__ G, const float* __restrict__ Bb,
                        u16* __restrict__ Out)
{
    const int row = blockIdx.x;
    const int t = threadIdx.x;
    const size_t idx = (size_t)row * E_ + t * 4;
    const short4v a0 = *(const short4v*)(P0 + idx);
    const short4v a1 = *(const short4v*)(P1 + idx);
    floatx4 v;
    for (int i = 0; i < 4; i++)
        v[i] = bf2f((u16)a0[i]) + bf2f((u16)a1[i]);
    float s  = v[0] + v[1] + v[2] + v[3];
    float ss = v[0] * v[0] + v[1] * v[1] + v[2] * v[2] + v[3] * v[3];
    for (int off = 32; off; off >>= 1) {
        s  += __shfl_down(s, off, 64);
        ss += __shfl_down(ss, off, 64);
    }
    __shared__ float red[8];
    const int wave = t >> 6, lane = t & 63;
    if (lane == 0) { red[wave] = s; red[4 + wave] = ss; }
    __syncthreads();
    const float S  = red[0] + red[1] + red[2] + red[3];
    const float SS = red[4] + red[5] + red[6] + red[7];
    const float mu  = S * (1.f / E_);
    const float var = SS * (1.f / E_) - mu * mu;
    const float rstd = rsqrtf(var + 1e-5f);

    short4v outv;
    for (int i = 0; i < 4; i++) {
        const int e = t * 4 + i;
        float y = (v[i] - mu) * rstd * G[e] + Bb[e];
        y *= bf2f(U[idx + i]);
        outv[i] = (short)f2bf(y);
    }
    *(short4v*)(Out + idx) = outv;
}

// ---------------------------------------------------------------------------
extern "C" void kernel_launch(void* const* d_in, const int* in_sizes, int n_in,
                              void* d_out, int out_size, void* d_ws, size_t ws_size,
                              hipStream_t stream)
{
    const float* x   = (const float*)d_in[0];
    const float* Wq  = (const float*)d_in[1];
    const float* bq  = (const float*)d_in[2];
    const float* Wk  = (const float*)d_in[3];
    const float* bk  = (const float*)d_in[4];
    const float* Wv  = (const float*)d_in[5];
    const float* bv  = (const float*)d_in[6];
    const float* Wu  = (const float*)d_in[7];
    const float* bu  = (const float*)d_in[8];
    const float* Wo  = (const float*)d_in[9];
    const float* bo  = (const float*)d_in[10];
    const float* lng = (const float*)d_in[11];
    const float* lnb = (const float*)d_in[12];

    char* ws = (char*)d_ws;
    u16*  qw  = (u16*)(ws);                      // 8 MB (q row-major, pre-scaled 1/8)
    u16*  kw  = (u16*)(ws + 8388608);            // 8 MB (K row-major)
    u16*  vw  = (u16*)(ws + 16777216);           // 8 MB (V row-major)
    u16*  uw  = (u16*)(ws + 25165824);           // 8 MB (u row-major)
    u16*  p0  = (u16*)(ws + 33554432);           // 8 MB bf16 attn partial z=0
    u16*  p1  = (u16*)(ws + 41943040);           // 8 MB bf16 attn partial z=1
    u16*  xb  = (u16*)(ws + 50331648);           // 8 MB x->bf16
    u16*  wbq = (u16*)(ws + 58720256);           // 2 MB each, bf16 weights
    u16*  wbk = (u16*)(ws + 60817408);
    u16*  wbv = (u16*)(ws + 62914560);
    u16*  wbu = (u16*)(ws + 65011712);
    u16*  wbo = (u16*)(ws + 67108864);
    u16*  gw  = (u16*)(ws);                      // reuses q buffer after attn

    float* out = (float*)d_out;

    // dtype prep (x + 5 weights, one launch)
    cvt6<<<dim3(M_TOT * E_ / 2048, 1, 6), dim3(256, 1, 1), 0, stream>>>(
        x, Wq, Wk, Wv, Wu, Wo, xb, wbq, wbk, wbv, wbu, wbo);
    // q,k,v,u projections: proven gemm4, no swizzle (silu on v,u; q scaled 1/8)
    gemm4<u16><<<dim3(8, 32, 4), dim3(256, 1, 1), 0, stream>>>(
        xb, wbq, wbk, wbv, wbu, bq, bk, bv, bu, qw, kw, vw, uw, 0xC, 0x1, E_);
    // attention v6 (proven 50.4 us): key-split x2, no swizzle, x32 PV
    attn<<<dim3(N_ / 256, B_ * H_, KSPLIT), dim3(256, 1, 1), 0, stream>>>(qw, kw, vw, p0, p1);
    // layernorm(sum of 2 partials) + gate
    ln_gate<<<dim3(M_TOT, 1, 1), dim3(256, 1, 1), 0, stream>>>(p0, p1, uw, lng, lnb, gw);
    // output projection -> fp32 d_out: 64x128 tiles, 3-buf pipelined
    gemm_out<<<dim3(E_ / 128, M_TOT / 64, 1), dim3(256, 1, 1), 0, stream>>>(gw, wbo, bo, out, E_);
}

// Round 8
// 211.944 us; speedup vs baseline: 1.6010x; 1.0189x over previous
//
#include <hip/hip_runtime.h>
#include <stdint.h>

typedef unsigned short u16;
typedef __attribute__((ext_vector_type(8))) short short8;
typedef __attribute__((ext_vector_type(4))) short short4v;
typedef __attribute__((ext_vector_type(4))) float floatx4;
typedef __attribute__((ext_vector_type(4))) int intx4;

#define B_ 2
#define N_ 2048
#define E_ 1024
#define H_ 16
#define HD_ 64
#define M_TOT (B_ * N_)   // 4096

__device__ __forceinline__ float bf2f(u16 h) {
    union { unsigned u; float f; } c; c.u = ((unsigned)h) << 16; return c.f;
}
__device__ __forceinline__ u16 f2bf(float f) {
    union { float f; unsigned u; } c; c.f = f;
    unsigned r = c.u + 0x7FFFu + ((c.u >> 16) & 1u);
    return (u16)(r >> 16);
}
__device__ __forceinline__ float silu_f(float x) { return x / (1.f + __expf(-x)); }

template <typename T> __device__ __forceinline__ void store_out(T* p, float v);
template <> __device__ __forceinline__ void store_out<u16>(u16* p, float v)    { *p = f2bf(v); }
template <> __device__ __forceinline__ void store_out<float>(float* p, float v) { *p = v; }

// Direct global->LDS 16B async copy. LDS dest = wave-uniform base + lane*16.
__device__ __forceinline__ void gll16(const void* g, void* l) {
    __builtin_amdgcn_global_load_lds(
        (const __attribute__((address_space(1))) void*)g,
        (__attribute__((address_space(3))) void*)l,
        16, 0, 0);
}

// relu(+pack) four fp32 -> 4 bf16 (round-half-up), order preserved.
__device__ __forceinline__ short4v relu_pack(floatx4 s) {
    union { float f; unsigned u; } c0, c1, c2, c3;
    c0.f = fmaxf(s[0], 0.f); c1.f = fmaxf(s[1], 0.f);
    c2.f = fmaxf(s[2], 0.f); c3.f = fmaxf(s[3], 0.f);
    unsigned lo = __builtin_amdgcn_perm(c1.u + 0x8000u, c0.u + 0x8000u, 0x07060302);
    unsigned hi = __builtin_amdgcn_perm(c3.u + 0x8000u, c2.u + 0x8000u, 0x07060302);
    union { unsigned v[2]; short4v s4; } r; r.v[0] = lo; r.v[1] = hi;
    return r.s4;
}

// ---------------------------------------------------------------------------
// fp32 -> bf16 for x (z=0, 2048 blocks) and 5 weights (z=1..5, 512 blocks).
// ---------------------------------------------------------------------------
__launch_bounds__(256, 4)
__global__ void cvt6(const float* __restrict__ s0, const float* __restrict__ s1,
                     const float* __restrict__ s2, const float* __restrict__ s3,
                     const float* __restrict__ s4, const float* __restrict__ s5,
                     u16* __restrict__ d0, u16* __restrict__ d1,
                     u16* __restrict__ d2, u16* __restrict__ d3,
                     u16* __restrict__ d4, u16* __restrict__ d5)
{
    const int z = blockIdx.z;
    if (z > 0 && blockIdx.x >= E_ * E_ / 2048) return;
    const float* src = (z == 0) ? s0 : (z == 1) ? s1 : (z == 2) ? s2
                     : (z == 3) ? s3 : (z == 4) ? s4 : s5;
    u16* dst         = (z == 0) ? d0 : (z == 1) ? d1 : (z == 2) ? d2
                     : (z == 3) ? d3 : (z == 4) ? d4 : d5;
    const int i = (blockIdx.x * 256 + threadIdx.x) * 8;
    floatx4 a = *(const floatx4*)(src + i);
    floatx4 b = *(const floatx4*)(src + i + 4);
    union { u16 h[8]; intx4 v; } o;
    o.h[0] = f2bf(a[0]); o.h[1] = f2bf(a[1]); o.h[2] = f2bf(a[2]); o.h[3] = f2bf(a[3]);
    o.h[4] = f2bf(b[0]); o.h[5] = f2bf(b[1]); o.h[6] = f2bf(b[2]); o.h[7] = f2bf(b[3]);
    *(intx4*)(dst + i) = o.v;
}

// ---------------------------------------------------------------------------
// GEMM (m97 structure, BK=32): C[M,1024] = act( A @ W^T + bias ) [*osc]
// The PROVEN projection kernel: 49.6-53.1 us across R1/R2/R7 replicas. NO
// blockIdx swizzle (measured +4 us, R5). Structural escapes all measured
// worse (R3 8-phase 77; R4 3-buf 66; R5 swizzle 57). HIP-source floor here.
// ---------------------------------------------------------------------------
template <typename OutT>
__launch_bounds__(256, 2)
__global__ void gemm4(const u16* __restrict__ A,
                      const u16* __restrict__ W0, const u16* __restrict__ W1,
                      const u16* __restrict__ W2, const u16* __restrict__ W3,
                      const float* __restrict__ bi0, const float* __restrict__ bi1,
                      const float* __restrict__ bi2, const float* __restrict__ bi3,
                      OutT* __restrict__ O0, OutT* __restrict__ O1,
                      OutT* __restrict__ O2, OutT* __restrict__ O3,
                      int actmask, int scalemask, int K)
{
    __shared__ u16 a_lds[128 * 32];   // 8 KB, unpadded (gll16 lane order)
    __shared__ u16 b_lds[128 * 32];

    const int z = blockIdx.z;
    const u16* W    = (z == 0) ? W0 : (z == 1) ? W1 : (z == 2) ? W2 : W3;
    const float* Bi = (z == 0) ? bi0 : (z == 1) ? bi1 : (z == 2) ? bi2 : bi3;
    OutT* Out       = (z == 0) ? O0 : (z == 1) ? O1 : (z == 2) ? O2 : O3;
    const bool act = (actmask >> z) & 1;
    const float osc = ((scalemask >> z) & 1) ? 0.125f : 1.0f;

    const int t    = threadIdx.x;
    const int wave = t >> 6, lane = t & 63, quad = lane >> 4, l16 = lane & 15;
    const int wm = wave >> 1, wn = wave & 1;
    const int m0 = blockIdx.y * 128;
    const int n0 = blockIdx.x * 128;

    floatx4 acc[4][4];
    const floatx4 fz = {0.f, 0.f, 0.f, 0.f};
    for (int i = 0; i < 4; i++)
        for (int j = 0; j < 4; j++) acc[i][j] = fz;

    // staging map: thread t -> LDS bytes [t*16, t*16+16) -> row t/4, col (t%4)*8
    const int ar = t >> 2;
    const int ac = (t & 3) * 8;
    const u16* Ag0 = A + (size_t)(m0 + ar) * K + ac;
    const u16* Ag1 = A + (size_t)(m0 + 64 + ar) * K + ac;
    const u16* Bg0 = W + (size_t)(n0 + ar) * K + ac;
    const u16* Bg1 = W + (size_t)(n0 + 64 + ar) * K + ac;
    u16* al0 = a_lds + wave * 512;
    u16* al1 = a_lds + 2048 + wave * 512;
    u16* bl0 = b_lds + wave * 512;
    u16* bl1 = b_lds + 2048 + wave * 512;

    for (int k0 = 0; k0 < K; k0 += 32) {
        __syncthreads();
        gll16(Ag0 + k0, al0);
        gll16(Ag1 + k0, al1);
        gll16(Bg0 + k0, bl0);
        gll16(Bg1 + k0, bl1);
        __syncthreads();

        short8 af[4], bfr[4];
        for (int i = 0; i < 4; i++)
            af[i]  = *(const short8*)&a_lds[(wm * 64 + i * 16 + l16) * 32 + quad * 8];
        for (int j = 0; j < 4; j++)
            bfr[j] = *(const short8*)&b_lds[(wn * 64 + j * 16 + l16) * 32 + quad * 8];
        for (int i = 0; i < 4; i++)
            for (int j = 0; j < 4; j++)
                acc[i][j] = __builtin_amdgcn_mfma_f32_16x16x32_bf16(af[i], bfr[j], acc[i][j], 0, 0, 0);
    }

    float bias_v[4];
    for (int j = 0; j < 4; j++) bias_v[j] = Bi[n0 + wn * 64 + j * 16 + l16];

    for (int i = 0; i < 4; i++) {
        const int row = m0 + wm * 64 + i * 16 + quad * 4;
        for (int j = 0; j < 4; j++) {
            const int col = n0 + wn * 64 + j * 16 + l16;
            for (int r = 0; r < 4; r++) {
                float v = acc[i][j][r] + bias_v[j];
                if (act) v = silu_f(v);
                v *= osc;
                store_out<OutT>(&Out[(size_t)(row + r) * E_ + col], v);
            }
        }
    }
}

// ---------------------------------------------------------------------------
// Output projection GEMM v2: 64x128 tile, 512 blocks (2/CU), 3-buffer 2-deep
// pipeline (counted vmcnt, never 0 mid-loop). Part of the best total (R3).
// ---------------------------------------------------------------------------
__launch_bounds__(256, 2)
__global__ void gemm_out(const u16* __restrict__ A, const u16* __restrict__ W,
                         const float* __restrict__ Bi, float* __restrict__ Out,
                         int K)
{
    __shared__ u16 a_lds[3][64 * 32];    // 3 x 4 KB
    __shared__ u16 b_lds[3][128 * 32];   // 3 x 8 KB  -> 36 KB total

    const int t    = threadIdx.x;
    const int wave = t >> 6, lane = t & 63, quad = lane >> 4, l16 = lane & 15;
    const int m0 = blockIdx.y * 64;
    const int n0 = blockIdx.x * 128;

    floatx4 acc[4][2];
    const floatx4 fz = {0.f, 0.f, 0.f, 0.f};
    for (int i = 0; i < 4; i++)
        for (int j = 0; j < 2; j++) acc[i][j] = fz;

    const int ar = t >> 2;
    const int ac = (t & 3) * 8;
    const u16* Ag0 = A + (size_t)(m0 + ar) * K + ac;
    const u16* Bg0 = W + (size_t)(n0 + ar) * K + ac;
    const u16* Bg1 = W + (size_t)(n0 + 64 + ar) * K + ac;

    const int nt = K / 32;

#define GO_STAGE(tt, bi) {                                      \
        gll16(Ag0 + (tt) * 32, &a_lds[bi][wave * 512]);         \
        gll16(Bg0 + (tt) * 32, &b_lds[bi][wave * 512]);         \
        gll16(Bg1 + (tt) * 32, &b_lds[bi][2048 + wave * 512]); }

    GO_STAGE(0, 0);
    GO_STAGE(1, 1);
    asm volatile("s_waitcnt vmcnt(3)" ::: "memory");   // tile 0 landed
    __builtin_amdgcn_s_barrier();

    for (int tt = 0; tt < nt; tt++) {
        const int bi = tt % 3;
        if (tt + 2 < nt) {
            GO_STAGE(tt + 2, (tt + 2) % 3);
        }
        short8 af[4], bfr[2];
#pragma unroll
        for (int i = 0; i < 4; i++)
            af[i]  = *(const short8*)&a_lds[bi][(i * 16 + l16) * 32 + quad * 8];
#pragma unroll
        for (int j = 0; j < 2; j++)
            bfr[j] = *(const short8*)&b_lds[bi][(wave * 32 + j * 16 + l16) * 32 + quad * 8];
#pragma unroll
        for (int i = 0; i < 4; i++)
#pragma unroll
            for (int j = 0; j < 2; j++)
                acc[i][j] = __builtin_amdgcn_mfma_f32_16x16x32_bf16(af[i], bfr[j], acc[i][j], 0, 0, 0);
        if (tt + 2 < nt) {
            asm volatile("s_waitcnt vmcnt(3)" ::: "memory");   // t+1 landed
        } else {
            asm volatile("s_waitcnt vmcnt(0)" ::: "memory");   // tail drain
        }
        __builtin_amdgcn_s_barrier();
    }
#undef GO_STAGE

    float bias_v[2];
    for (int j = 0; j < 2; j++) bias_v[j] = Bi[n0 + wave * 32 + j * 16 + l16];

    for (int i = 0; i < 4; i++) {
        const int row = m0 + i * 16 + quad * 4;
        for (int j = 0; j < 2; j++) {
            const int col = n0 + wave * 32 + j * 16 + l16;
            for (int r = 0; r < 4; r++)
                Out[(size_t)(row + r) * E_ + col] = acc[i][j][r] + bias_v[j];
        }
    }
}

// ---------------------------------------------------------------------------
// Attention v7 (RESTORED from R3, the best-total round): O = relu(Q K^T) @ V,
// Q pre-scaled 1/8. KSPLIT=2, NO swizzle. T14 async-STAGE split + LDS
// double-buffer: per 64-key tile, issue tile t+1's global loads BEFORE
// compute(t) (latency hides under MFMA), ds_write into buf^1 AFTER, one
// __syncthreads per tile (v6 had 2 + naked load latency between them).
// Ledger evidence: R3 (this attn, gemm8p@77) = 207.6 vs R7 (attn v6,
// gemm4@50) = 216 -> v6->v7 + the 27us slower projection = -8.4 net, i.e.
// v7 carries ~-30us in composition. This round isolates it against gemm4.
// ---------------------------------------------------------------------------
#define LK 72
#define LV 72
#define KSPLIT 2
#define KCHUNK (N_ / KSPLIT)    // 1024 keys per z
#define NKT (KCHUNK / 64)       // 16 tiles

__launch_bounds__(256, 2)
__global__ void attn(const u16* __restrict__ Q, const u16* __restrict__ Kk,
                     const u16* __restrict__ V,
                     u16* __restrict__ P0, u16* __restrict__ P1)
{
    __shared__ u16 k_lds[2][64 * LK];    // row-permuted [keyslot][d], dbuf
    __shared__ u16 v_lds[2][64 * LV];    // [d][key], padded stride, dbuf

    const int bh = blockIdx.y;
    const int b = bh >> 4, h = bh & 15;
    const int z = blockIdx.z;
    u16* __restrict__ Oa = (z == 0) ? P0 : P1;
    const int key_base = z * KCHUNK;

    const int t = threadIdx.x;
    const int wave = t >> 6, lane = t & 63, quad = lane >> 4, l16 = lane & 15;
    const int q0 = blockIdx.x * 256 + wave * 64;
    const size_t base = (size_t)b * N_ * E_ + h * HD_;

    short8 aq[4][2];
    for (int mi = 0; mi < 4; mi++)
        for (int ks = 0; ks < 2; ks++)
            aq[mi][ks] = *(const short8*)(Q + base + (size_t)(q0 + mi * 16 + l16) * E_ + ks * 32 + quad * 8);

    floatx4 o[4][4];
    const floatx4 fz = {0.f, 0.f, 0.f, 0.f};
    for (int mi = 0; mi < 4; mi++)
        for (int nd = 0; nd < 4; nd++) o[mi][nd] = fz;

    const int srow = t >> 2, sseg = (t & 3) * 16;
    const int prow = (srow & 32) + (((srow >> 2) & 1) << 4)
                   + (((srow >> 3) & 3) << 2) + (srow & 3);
    const u16* Ksrc = Kk + base + (size_t)(key_base + srow) * E_ + sseg;
    const u16* Vsrc = V + base + (size_t)(key_base + srow) * E_ + sseg;
    const int kofs = prow * LK + sseg;

    // prologue: tile 0 -> regs -> buf0
    intx4 kv0 = *(const intx4*)(Ksrc);
    intx4 kv1 = *(const intx4*)(Ksrc + 8);
    intx4 vv0 = *(const intx4*)(Vsrc);
    intx4 vv1 = *(const intx4*)(Vsrc + 8);
    {
        *(intx4*)(&k_lds[0][kofs])     = kv0;
        *(intx4*)(&k_lds[0][kofs + 8]) = kv1;
        const u16* v0p = (const u16*)&vv0;
        const u16* v1p = (const u16*)&vv1;
        for (int i = 0; i < 8; i++) {
            v_lds[0][(sseg + i) * LV + srow]     = v0p[i];
            v_lds[0][(sseg + 8 + i) * LV + srow] = v1p[i];
        }
    }

    for (int kt = 0; kt < NKT; kt++) {
        __syncthreads();    // buf[kt&1] writes visible; prev reads of buf^1 done
        const int cur = kt & 1;

        // issue next tile's global loads NOW (hide under compute)
        if (kt + 1 < NKT) {
            const u16* kg = Ksrc + (size_t)((kt + 1) * 64) * E_;
            const u16* vg = Vsrc + (size_t)((kt + 1) * 64) * E_;
            kv0 = *(const intx4*)(kg);
            kv1 = *(const intx4*)(kg + 8);
            vv0 = *(const intx4*)(vg);
            vv1 = *(const intx4*)(vg + 8);
        }

        for (int g = 0; g < 2; g++) {   // 32-key group
            short8 ka[2][2];
            for (int tp = 0; tp < 2; tp++)
                for (int ks = 0; ks < 2; ks++)
                    ka[tp][ks] = *(const short8*)&k_lds[cur][(g * 32 + tp * 16 + l16) * LK + ks * 32 + quad * 8];
            short8 bv[4];
            for (int nd = 0; nd < 4; nd++)
                bv[nd] = *(const short8*)&v_lds[cur][(nd * 16 + l16) * LV + g * 32 + quad * 8];

            for (int mi = 0; mi < 4; mi++) {
                floatx4 c0 = __builtin_amdgcn_mfma_f32_16x16x32_bf16(ka[0][0], aq[mi][0], fz, 0, 0, 0);
                c0 = __builtin_amdgcn_mfma_f32_16x16x32_bf16(ka[0][1], aq[mi][1], c0, 0, 0, 0);
                floatx4 c1 = __builtin_amdgcn_mfma_f32_16x16x32_bf16(ka[1][0], aq[mi][0], fz, 0, 0, 0);
                c1 = __builtin_amdgcn_mfma_f32_16x16x32_bf16(ka[1][1], aq[mi][1], c1, 0, 0, 0);
                union { short4v h[2]; short8 s8; } sf;
                sf.h[0] = relu_pack(c0);
                sf.h[1] = relu_pack(c1);
                for (int nd = 0; nd < 4; nd++)
                    o[mi][nd] = __builtin_amdgcn_mfma_f32_16x16x32_bf16(sf.s8, bv[nd], o[mi][nd], 0, 0, 0);
            }
        }

        // write next tile into buf^1 (its prior readers finished before this
        // iteration's top barrier)
        if (kt + 1 < NKT) {
            const int nxt = cur ^ 1;
            *(intx4*)(&k_lds[nxt][kofs])     = kv0;
            *(intx4*)(&k_lds[nxt][kofs + 8]) = kv1;
            const u16* v0p = (const u16*)&vv0;
            const u16* v1p = (const u16*)&vv1;
            for (int i = 0; i < 8; i++) {
                v_lds[nxt][(sseg + i) * LV + srow]     = v0p[i];
                v_lds[nxt][(sseg + 8 + i) * LV + srow] = v1p[i];
            }
        }
    }

    for (int mi = 0; mi < 4; mi++)
        for (int nd = 0; nd < 4; nd++)
            for (int r = 0; r < 4; r++)
                Oa[(size_t)(b * N_ + q0 + mi * 16 + quad * 4 + r) * E_ + h * HD_ + nd * 16 + l16] =
                    f2bf(o[mi][nd][r]);
}

// ---------------------------------------------------------------------------
// LayerNorm over E=1024 of (P0+P1) + gate by u, emit bf16. 1 block/row.
// ---------------------------------------------------------------------------
__launch_bounds__(256, 4)
__global__ void ln_gate(const u16* __restrict__ P0, const u16* __restrict__ P1,
                        const u16* __restrict__ U,
                        const float* __restrict__ G, const float* __restrict__ Bb,
                        u16* __restrict__ Out)
{
    const int row = blockIdx.x;
    const int t = threadIdx.x;
    const size_t idx = (size_t)row * E_ + t * 4;
    const short4v a0 = *(const short4v*)(P0 + idx);
    const short4v a1 = *(const short4v*)(P1 + idx);
    floatx4 v;
    for (int i = 0; i < 4; i++)
        v[i] = bf2f((u16)a0[i]) + bf2f((u16)a1[i]);
    float s  = v[0] + v[1] + v[2] + v[3];
    float ss = v[0] * v[0] + v[1] * v[1] + v[2] * v[2] + v[3] * v[3];
    for (int off = 32; off; off >>= 1) {
        s  += __shfl_down(s, off, 64);
        ss += __shfl_down(ss, off, 64);
    }
    __shared__ float red[8];
    const int wave = t >> 6, lane = t & 63;
    if (lane == 0) { red[wave] = s; red[4 + wave] = ss; }
    __syncthreads();
    const float S  = red[0] + red[1] + red[2] + red[3];
    const float SS = red[4] + red[5] + red[6] + red[7];
    const float mu  = S * (1.f / E_);
    const float var = SS * (1.f / E_) - mu * mu;
    const float rstd = rsqrtf(var + 1e-5f);

    short4v outv;
    for (int i = 0; i < 4; i++) {
        const int e = t * 4 + i;
        float y = (v[i] - mu) * rstd * G[e] + Bb[e];
        y *= bf2f(U[idx + i]);
        outv[i] = (short)f2bf(y);
    }
    *(short4v*)(Out + idx) = outv;
}

// ---------------------------------------------------------------------------
extern "C" void kernel_launch(void* const* d_in, const int* in_sizes, int n_in,
                              void* d_out, int out_size, void* d_ws, size_t ws_size,
                              hipStream_t stream)
{
    const float* x   = (const float*)d_in[0];
    const float* Wq  = (const float*)d_in[1];
    const float* bq  = (const float*)d_in[2];
    const float* Wk  = (const float*)d_in[3];
    const float* bk  = (const float*)d_in[4];
    const float* Wv  = (const float*)d_in[5];
    const float* bv  = (const float*)d_in[6];
    const float* Wu  = (const float*)d_in[7];
    const float* bu  = (const float*)d_in[8];
    const float* Wo  = (const float*)d_in[9];
    const float* bo  = (const float*)d_in[10];
    const float* lng = (const float*)d_in[11];
    const float* lnb = (const float*)d_in[12];

    char* ws = (char*)d_ws;
    u16*  qw  = (u16*)(ws);                      // 8 MB (q row-major, pre-scaled 1/8)
    u16*  kw  = (u16*)(ws + 8388608);            // 8 MB (K row-major)
    u16*  vw  = (u16*)(ws + 16777216);           // 8 MB (V row-major)
    u16*  uw  = (u16*)(ws + 25165824);           // 8 MB (u row-major)
    u16*  p0  = (u16*)(ws + 33554432);           // 8 MB bf16 attn partial z=0
    u16*  p1  = (u16*)(ws + 41943040);           // 8 MB bf16 attn partial z=1
    u16*  xb  = (u16*)(ws + 50331648);           // 8 MB x->bf16
    u16*  wbq = (u16*)(ws + 58720256);           // 2 MB each, bf16 weights
    u16*  wbk = (u16*)(ws + 60817408);
    u16*  wbv = (u16*)(ws + 62914560);
    u16*  wbu = (u16*)(ws + 65011712);
    u16*  wbo = (u16*)(ws + 67108864);
    u16*  gw  = (u16*)(ws);                      // reuses q buffer after attn

    float* out = (float*)d_out;

    // dtype prep (x + 5 weights, one launch)
    cvt6<<<dim3(M_TOT * E_ / 2048, 1, 6), dim3(256, 1, 1), 0, stream>>>(
        x, Wq, Wk, Wv, Wu, Wo, xb, wbq, wbk, wbv, wbu, wbo);
    // q,k,v,u projections: proven gemm4, no swizzle (silu on v,u; q scaled 1/8)
    gemm4<u16><<<dim3(8, 32, 4), dim3(256, 1, 1), 0, stream>>>(
        xb, wbq, wbk, wbv, wbu, bq, bk, bv, bu, qw, kw, vw, uw, 0xC, 0x1, E_);
    // attention v7 (async-stage dbuf, from best-total R3): key-split x2
    attn<<<dim3(N_ / 256, B_ * H_, KSPLIT), dim3(256, 1, 1), 0, stream>>>(qw, kw, vw, p0, p1);
    // layernorm(sum of 2 partials) + gate
    ln_gate<<<dim3(M_TOT, 1, 1), dim3(256, 1, 1), 0, stream>>>(p0, p1, uw, lng, lnb, gw);
    // output projection -> fp32 d_out: 64x128 tiles, 3-buf pipelined
    gemm_out<<<dim3(E_ / 128, M_TOT / 64, 1), dim3(256, 1, 1), 0, stream>>>(gw, wbo, bo, out, E_);
}